// Round 17
// baseline (1566.013 us; speedup 1.0000x reference)
//
#include <hip/hip_runtime.h>

#define T_STEPS 512
#define B_ROWS  64
#define F_DIM   256
#define U_DIM   1024
#define G3      3072   // 3*U
#define PACC_BYTES (2 * 12 * 64 * 16)     // parity x (4acc x 3waves) x 64 lanes x 16B
#define LDS_BYTES (PACC_BYTES + 512)

// h exchange: 5-slot rotation of [4 rowtile groups][64 tiles][512 B].
// Sentinel protocol (r8/r10/r11/r16, proven): data IS the signal; tiles
// re-poisoned with bf16-NaN 3 slots ahead; ordering via the poll vmcnt(0).
// System scope (sc0 sc1) mandatory (r14: sc1-only deadlocks cross-XCD).
// Single-set poll with FULL vmcnt(0) (r14/r15: counted-vmcnt ping-pong hangs).
// NEW vs r16: the pre-poll window contains ONLY the 8 h-loads — x(t+1) is
// register-prefetched post-detect, and wave0's out-stores moved post-detect,
// so the poll's vmcnt(0) never waits on HBM x-fetches or out-store acks.
#define NSLOT  5
#define TILE_B 512
#define GRP_B  (64 * TILE_B)      // 32 KB per rowtile group
#define SLOT_B (4 * GRP_B)        // 128 KB per slot
#define SENT   0x7FC17FC1u        // 2x bf16 NaN — h is always finite

typedef __bf16 bf16x8 __attribute__((ext_vector_type(8)));
typedef float  f32x4  __attribute__((ext_vector_type(4)));
typedef unsigned int u32x2 __attribute__((ext_vector_type(2)));
typedef unsigned int u32x4 __attribute__((ext_vector_type(4)));

__device__ __forceinline__ float sigmoidf_(float v) {
    return 1.f / (1.f + __expf(-v));
}
__device__ __forceinline__ float tanhf_(float v) {
    float e2 = __expf(2.f * v);
    return 1.f - 2.f / (e2 + 1.f);
}

// ---------------------------------------------------------------------------
// Transpose + cvt recurrent kernel: [1024][3072] f32 -> [3072][1024] bf16
// ---------------------------------------------------------------------------
__global__ __launch_bounds__(256) void transpose_cvt_kernel(
    const float* __restrict__ src, __bf16* __restrict__ dst, int Kdim)
{
    __shared__ float tile[32][33];
    const int n0 = blockIdx.x * 32;
    const int k0 = blockIdx.y * 32;
    const int j  = threadIdx.x & 31;
    const int i0 = threadIdx.x >> 5;
#pragma unroll
    for (int s = 0; s < 4; ++s) {
        int i = i0 * 4 + s;
        tile[i][j] = src[(size_t)(k0 + i) * G3 + n0 + j];
    }
    __syncthreads();
#pragma unroll
    for (int s = 0; s < 4; ++s) {
        int i = i0 * 4 + s;
        dst[(size_t)(n0 + i) * Kdim + k0 + j] = (__bf16)tile[j][i];
    }
}

// ---------------------------------------------------------------------------
// Init: hidden f32 -> bf16 tiles in slot 0; slots 1..4 = sentinel.
// ---------------------------------------------------------------------------
__global__ __launch_bounds__(256) void init_kernel(
    const float* __restrict__ hidden, char* __restrict__ rot)
{
    const int i = blockIdx.x * 256 + threadIdx.x;   // 0..65535
    const int row = i >> 10, u = i & 1023;
    const int rt = row >> 4, rl = row & 15, c = u >> 4, ul = u & 15;
    *(__bf16*)(rot + rt * GRP_B + c * TILE_B + ((rl << 4) + ul) * 2) =
        (__bf16)hidden[i];
    unsigned* s = (unsigned*)(rot + SLOT_B);        // slots 1..4
    s[2 * i]     = SENT;
    s[2 * i + 1] = SENT;
}

// ---------------------------------------------------------------------------
// Persistent GRU. Grid = 256 blocks x 256 threads (4 waves, 1 block/CU).
// r11/r16 skeleton: wave w owns H k-slice [256w,256w+256) and X k-slice
// [64w,64w+64); ALL B-fragments in registers; LDS only for partial-acc
// exchange + pack tile; wave0 runs the epilogue.
// Per step: issue 8 h-loads (slot t%5) -> X-GEMM (x from PREFETCHED regs)
// -> poll vmcnt(0) [waits only the h-loads] -> detect -> prefetch x(t+1) +
// wave0 out[t-1] stores (drain under H/sync/epilogue) -> H-GEMM -> dump ->
// sync -> wave0: reduce + gates + pack + publish + poison (t+3)%5.
// ---------------------------------------------------------------------------
__global__ __launch_bounds__(256, 1) void gru_persistent(
    const float* __restrict__ x,       // [64][512][256] f32
    const float* __restrict__ hidden,  // [64][1024] f32
    const float* __restrict__ bias,    // [2][3072] f32
    const float* __restrict__ kern,    // [256][3072] f32 (input kernel)
    const __bf16* __restrict__ Rt,     // [3072][1024] bf16
    char* __restrict__ rot,            // NSLOT * SLOT_B bytes
    float* __restrict__ out)           // [64][512][1024] f32 (+ state tail)
{
    extern __shared__ char lds_raw[];
    float*  pacc  = (float*)lds_raw;
    __bf16* hpack = (__bf16*)(lds_raw + PACC_BYTES); // [16][16]

    const int tid  = threadIdx.x;
    const int lane = tid & 63;
    const int wv   = tid >> 6;        // 0..3
    const int rc   = lane & 15;
    const int kg   = lane >> 4;
    const int bid  = blockIdx.x;
    const int c    = bid & 63;
    const int rt   = bid >> 6;
    const int u    = (c << 4) + rc;
    const int row0 = rt << 4;

    if (wv == 0) __builtin_amdgcn_s_setprio(1);

    const int gu0 = u;
    const int gu1 = U_DIM + u;
    const int gu2 = 2 * U_DIM + u;
    const int xk0 = wv << 6;          // X k-slice base

    // ---- hoist ALL B-fragments into registers (once) ----
    bf16x8 whz[8], whr[8], whh[8];    // H-weights: contiguous 16B from Rt
#pragma unroll
    for (int ki = 0; ki < 8; ++ki) {
        const int col = (wv << 8) + (ki << 5) + (kg << 3);
        whz[ki] = *(const bf16x8*)(Rt + (size_t)gu0 * U_DIM + col);
        whr[ki] = *(const bf16x8*)(Rt + (size_t)gu1 * U_DIM + col);
        whh[ki] = *(const bf16x8*)(Rt + (size_t)gu2 * U_DIM + col);
    }
    bf16x8 wxz[2], wxr[2], wxh[2];    // X-weights: scattered one-time f32
#pragma unroll
    for (int fx = 0; fx < 2; ++fx) {
#pragma unroll
        for (int e = 0; e < 8; ++e) {
            const int k = xk0 + fx * 32 + (kg << 3) + e;
            wxz[fx][e] = (__bf16)kern[(size_t)k * G3 + gu0];
            wxr[fx][e] = (__bf16)kern[(size_t)k * G3 + gu1];
            wxh[fx][e] = (__bf16)kern[(size_t)k * G3 + gu2];
        }
    }

    // ---- per-thread invariants ----
    float hprev[4];
#pragma unroll
    for (int j = 0; j < 4; ++j)
        hprev[j] = hidden[(size_t)(row0 + (kg << 2) + j) * U_DIM + u];

    const float bz_ = bias[u]             + bias[G3 + u];
    const float br_ = bias[U_DIM + u]     + bias[G3 + U_DIM + u];
    const float bhx = bias[2 * U_DIM + u];
    const float bhr = bias[G3 + 2 * U_DIM + u];

    const float* xbase = x + (size_t)(row0 + rc) * (T_STEPS * F_DIM)
                           + xk0 + (kg << 3);

    const int grp_b = rt * GRP_B;
    const int lan_b = (wv << 13) + ((kg >> 1) << 9) + (rc << 5) + ((kg & 1) << 4);
    const int my_b  = grp_b + c * TILE_B + (lane << 3);

    int slot_r = 0, slot_w = 1, slot_p = 3;
    const u32x2 sentv = { SENT, SENT };

    // ---- x register prefetch, one step deep: load x(0) now ----
    float4 xcur0, xcur1, xcur2, xcur3, xnxt0, xnxt1, xnxt2, xnxt3;
    xcur0 = *(const float4*)(xbase + 0);
    xcur1 = *(const float4*)(xbase + 4);
    xcur2 = *(const float4*)(xbase + 32);
    xcur3 = *(const float4*)(xbase + 36);

    for (int t = 0; t < T_STEPS; ++t) {
        f32x4 accZ  = {0.f, 0.f, 0.f, 0.f};
        f32x4 accR  = {0.f, 0.f, 0.f, 0.f};
        f32x4 accHX = {0.f, 0.f, 0.f, 0.f};
        f32x4 accHR = {0.f, 0.f, 0.f, 0.f};
        const int p = t & 1;

        // ---- spec-issue my 8 h(t-1) fragment loads (slot t%5) ----
        const char* hb = rot + slot_r * SLOT_B + grp_b + lan_b;
        bf16x8 hfrag[8];
#define HL(ki, m, lit)                                                         \
        asm volatile("global_load_dwordx4 %0, %1, off offset:" lit " sc0 sc1"  \
                     : "=v"(hfrag[ki]) : "v"(hb + (m) * 4096) : "memory");
#define HLOADS()                                                               \
        HL(0,0,"0") HL(1,0,"1024") HL(2,0,"2048") HL(3,0,"3072")               \
        HL(4,1,"0") HL(5,1,"1024") HL(6,1,"2048") HL(7,1,"3072")
        HLOADS()

        // ---- X phase: my 64-k slice, A from prefetched regs, B from regs ----
        {
            const float4 xa[4] = { xcur0, xcur1, xcur2, xcur3 };
#pragma unroll
            for (int fx = 0; fx < 2; ++fx) {
                const float4 a0 = xa[fx * 2];
                const float4 a1 = xa[fx * 2 + 1];
                bf16x8 af;
                af[0] = (__bf16)a0.x; af[1] = (__bf16)a0.y;
                af[2] = (__bf16)a0.z; af[3] = (__bf16)a0.w;
                af[4] = (__bf16)a1.x; af[5] = (__bf16)a1.y;
                af[6] = (__bf16)a1.z; af[7] = (__bf16)a1.w;
                accZ  = __builtin_amdgcn_mfma_f32_16x16x32_bf16(af, wxz[fx], accZ,  0, 0, 0);
                accR  = __builtin_amdgcn_mfma_f32_16x16x32_bf16(af, wxr[fx], accR,  0, 0, 0);
                accHX = __builtin_amdgcn_mfma_f32_16x16x32_bf16(af, wxh[fx], accHX, 0, 0, 0);
            }
        }

        // ---- sentinel poll: vmcnt(0) covers ONLY the 8 h-loads ----
        for (;;) {
            asm volatile("s_waitcnt vmcnt(0)" ::: "memory");
            __builtin_amdgcn_sched_barrier(0);
            int ok = 1;
#pragma unroll
            for (int ki = 0; ki < 8; ++ki) {
                const u32x4 w = __builtin_bit_cast(u32x4, hfrag[ki]);
                ok &= (w[0] != SENT) & (w[2] != SENT);
            }
            if (__all(ok)) break;
            HLOADS()
        }
#undef HLOADS
#undef HL

        // ---- post-detect: issue x(t+1) prefetch (drains under H/sync/epi) ----
        {
            const int tn = (t + 1 < T_STEPS) ? (t + 1) : t;
            const float* apn = xbase + (size_t)tn * F_DIM;
            xnxt0 = *(const float4*)(apn + 0);
            xnxt1 = *(const float4*)(apn + 4);
            xnxt2 = *(const float4*)(apn + 32);
            xnxt3 = *(const float4*)(apn + 36);
        }
        // ---- post-detect: wave0 out[t-1] stores (acks drain off-path) ----
        if (wv == 0 && t > 0) {
#pragma unroll
            for (int j = 0; j < 4; ++j) {
                const int row = row0 + (kg << 2) + j;
                out[((size_t)row * T_STEPS + (t - 1)) * U_DIM + u] = hprev[j];
            }
        }

        // ---- H phase: 24 pure-register MFMAs ----
#pragma unroll
        for (int ki = 0; ki < 8; ++ki) {
            const bf16x8 af = hfrag[ki];
            accZ  = __builtin_amdgcn_mfma_f32_16x16x32_bf16(af, whz[ki], accZ,  0, 0, 0);
            accR  = __builtin_amdgcn_mfma_f32_16x16x32_bf16(af, whr[ki], accR,  0, 0, 0);
            accHR = __builtin_amdgcn_mfma_f32_16x16x32_bf16(af, whh[ki], accHR, 0, 0, 0);
        }

        // ---- waves 1-3: dump partials (parity-buffered) ----
        if (wv != 0) {
            const int w1 = wv - 1;
            *(f32x4*)&pacc[(((p * 12) + 0 * 3 + w1) * 64 + lane) * 4] = accZ;
            *(f32x4*)&pacc[(((p * 12) + 1 * 3 + w1) * 64 + lane) * 4] = accR;
            *(f32x4*)&pacc[(((p * 12) + 2 * 3 + w1) * 64 + lane) * 4] = accHX;
            *(f32x4*)&pacc[(((p * 12) + 3 * 3 + w1) * 64 + lane) * 4] = accHR;
        }
        __syncthreads();

        // ---- wave 0: reduce, gates, publish (single 8B store), poison ----
        if (wv == 0) {
#pragma unroll
            for (int w1 = 0; w1 < 3; ++w1) {
                accZ  += *(const f32x4*)&pacc[(((p * 12) + 0 * 3 + w1) * 64 + lane) * 4];
                accR  += *(const f32x4*)&pacc[(((p * 12) + 1 * 3 + w1) * 64 + lane) * 4];
                accHX += *(const f32x4*)&pacc[(((p * 12) + 2 * 3 + w1) * 64 + lane) * 4];
                accHR += *(const f32x4*)&pacc[(((p * 12) + 3 * 3 + w1) * 64 + lane) * 4];
            }
#pragma unroll
            for (int j = 0; j < 4; ++j) {
                const float z  = sigmoidf_(accZ[j] + bz_);
                const float r  = sigmoidf_(accR[j] + br_);
                const float hh = tanhf_(accHX[j] + bhx + r * (accHR[j] + bhr));
                hprev[j] = z * hprev[j] + (1.f - z) * hh;
            }
#pragma unroll
            for (int j = 0; j < 4; ++j)
                hpack[(((kg << 2) + j) << 4) + rc] = (__bf16)hprev[j];
            const u32x2 hv = *(const u32x2*)(hpack + ((lane >> 2) << 4) + ((lane & 3) << 2));
            asm volatile("global_store_dwordx2 %0, %1, off sc0 sc1"
                         :: "v"(rot + slot_w * SLOT_B + my_b), "v"(hv) : "memory");
            asm volatile("global_store_dwordx2 %0, %1, off sc0 sc1"
                         :: "v"(rot + slot_p * SLOT_B + my_b), "v"(sentv) : "memory");
        }

        // ---- rotate x prefetch registers (wait lands here, post-epilogue) ----
        xcur0 = xnxt0; xcur1 = xnxt1; xcur2 = xnxt2; xcur3 = xnxt3;

        if (++slot_r == NSLOT) slot_r = 0;
        if (++slot_w == NSLOT) slot_w = 0;
        if (++slot_p == NSLOT) slot_p = 0;
    }

    // ---- final: out[T-1] + state tail (wave 0) ----
    if (wv == 0) {
#pragma unroll
        for (int j = 0; j < 4; ++j) {
            const int row = row0 + (kg << 2) + j;
            out[((size_t)row * T_STEPS + (T_STEPS - 1)) * U_DIM + u] = hprev[j];
            out[(size_t)B_ROWS * T_STEPS * U_DIM + (size_t)row * U_DIM + u] = hprev[j];
        }
    }
}

extern "C" void kernel_launch(void* const* d_in, const int* in_sizes, int n_in,
                              void* d_out, int out_size, void* d_ws, size_t ws_size,
                              hipStream_t stream)
{
    const float* x      = (const float*)d_in[0];  // [64,512,256]
    const float* hidden = (const float*)d_in[1];  // [64,1024]
    const float* kernel = (const float*)d_in[2];  // [256,3072]
    const float* rker   = (const float*)d_in[3];  // [1024,3072]
    const float* bias   = (const float*)d_in[4];  // [2,3072]
    float* out = (float*)d_out;

    const size_t rt_el = (size_t)G3 * U_DIM;
    __bf16* Rt = (__bf16*)d_ws;                   // 6.29 MB
    char* rot  = (char*)(Rt + rt_el);             // 640 KB (5 slots)

    hipLaunchKernelGGL(transpose_cvt_kernel, dim3(G3 / 32, U_DIM / 32), dim3(256),
                       0, stream, rker, Rt, U_DIM);
    hipLaunchKernelGGL(init_kernel, dim3(256), dim3(256), 0, stream, hidden, rot);

    void* kx = (void*)&x;  void* kh = (void*)&hidden; void* kb = (void*)&bias;
    void* kk = (void*)&kernel; void* kR = (void*)&Rt;
    void* kr = (void*)&rot; void* ko = (void*)&out;
    void* args[7] = { kx, kh, kb, kk, kR, kr, ko };

    auto kfn = gru_persistent;
    (void)hipFuncSetAttribute((const void*)kfn,
                              hipFuncAttributeMaxDynamicSharedMemorySize, LDS_BYTES);
    hipError_t ce = hipLaunchCooperativeKernel(kfn, dim3(256), dim3(256), args,
                                               LDS_BYTES, stream);
    if (ce != hipSuccess) {
        // Fallback: plain launch. 1 block/CU on 256 CUs -> all blocks
        // co-resident; the spin protocol remains deadlock-free.
        hipLaunchKernelGGL(gru_persistent, dim3(256), dim3(256), LDS_BYTES, stream,
                           x, hidden, bias, kernel, Rt, rot, out);
    }
}

// Round 18
// 1391.600 us; speedup vs baseline: 1.1253x; 1.1253x over previous
//
#include <hip/hip_runtime.h>

#define T_STEPS 512
#define B_ROWS  64
#define F_DIM   256
#define U_DIM   1024
#define G3      3072   // 3*U
#define PACC_BYTES (2 * 12 * 64 * 16)     // parity x (4acc x 3waves) x 64 lanes x 16B
#define LDS_BYTES (PACC_BYTES + 512)

// h exchange: 5-slot rotation of [4 rowtile groups][64 tiles][512 B].
// Sentinel protocol (r8/r10/r11/r16, proven): data IS the signal; tiles
// re-poisoned with bf16-NaN 3 slots ahead; ordering via the poll vmcnt(0).
// System scope (sc0 sc1) mandatory (r14: sc1-only deadlocks cross-XCD).
// Single-set poll with FULL vmcnt(0) (r14/r15: counted-vmcnt ping-pong hangs).
// r17 note: x-register-prefetch regressed (compiler wait placement) — x loads
// stay in the X phase, where the poll's drain absorbs them for free.
#define NSLOT  5
#define TILE_B 512
#define GRP_B  (64 * TILE_B)      // 32 KB per rowtile group
#define SLOT_B (4 * GRP_B)        // 128 KB per slot
#define SENT   0x7FC17FC1u        // 2x bf16 NaN — h is always finite

typedef __bf16 bf16x8 __attribute__((ext_vector_type(8)));
typedef float  f32x4  __attribute__((ext_vector_type(4)));
typedef unsigned int u32x2 __attribute__((ext_vector_type(2)));
typedef unsigned int u32x4 __attribute__((ext_vector_type(4)));

__device__ __forceinline__ float sigmoidf_(float v) {
    return 1.f / (1.f + __expf(-v));
}
__device__ __forceinline__ float tanhf_(float v) {
    float e2 = __expf(2.f * v);
    return 1.f - 2.f / (e2 + 1.f);
}

// ---------------------------------------------------------------------------
// Transpose + cvt recurrent kernel: [1024][3072] f32 -> [3072][1024] bf16
// ---------------------------------------------------------------------------
__global__ __launch_bounds__(256) void transpose_cvt_kernel(
    const float* __restrict__ src, __bf16* __restrict__ dst, int Kdim)
{
    __shared__ float tile[32][33];
    const int n0 = blockIdx.x * 32;
    const int k0 = blockIdx.y * 32;
    const int j  = threadIdx.x & 31;
    const int i0 = threadIdx.x >> 5;
#pragma unroll
    for (int s = 0; s < 4; ++s) {
        int i = i0 * 4 + s;
        tile[i][j] = src[(size_t)(k0 + i) * G3 + n0 + j];
    }
    __syncthreads();
#pragma unroll
    for (int s = 0; s < 4; ++s) {
        int i = i0 * 4 + s;
        dst[(size_t)(n0 + i) * Kdim + k0 + j] = (__bf16)tile[j][i];
    }
}

// ---------------------------------------------------------------------------
// Init: hidden f32 -> bf16 tiles in slot 0; slots 1..4 = sentinel.
// ---------------------------------------------------------------------------
__global__ __launch_bounds__(256) void init_kernel(
    const float* __restrict__ hidden, char* __restrict__ rot)
{
    const int i = blockIdx.x * 256 + threadIdx.x;   // 0..65535
    const int row = i >> 10, u = i & 1023;
    const int rt = row >> 4, rl = row & 15, c = u >> 4, ul = u & 15;
    *(__bf16*)(rot + rt * GRP_B + c * TILE_B + ((rl << 4) + ul) * 2) =
        (__bf16)hidden[i];
    unsigned* s = (unsigned*)(rot + SLOT_B);        // slots 1..4
    s[2 * i]     = SENT;
    s[2 * i + 1] = SENT;
}

// ---------------------------------------------------------------------------
// Persistent GRU. Grid = 256 blocks x 256 threads (4 waves, 1 block/CU,
// 1 wave/SIMD -> ~450 VGPR budget/wave). Block (rt=bid>>6, c=bid&63).
// K-SPLIT: wave w owns H k-slice [256w,256w+256) and X k-slice [64w,64w+64).
// ALL B-fragments (30 x bf16x8 = 120 VGPR) live in REGISTERS — zero LDS
// reads in the step loop except the partial-acc exchange.
// Per step: spec-issue 8 h-loads (slot t%5) -> X-GEMM (regs) -> wave0 out[t-1]
// -> sentinel poll -> H-GEMM (regs) -> dump partials -> sync -> wave0:
// reduce + gates + pack + ONE 8B publish store/lane + poison (t+3)%5.
// ---------------------------------------------------------------------------
__global__ __launch_bounds__(256, 1) void gru_persistent(
    const float* __restrict__ x,       // [64][512][256] f32
    const float* __restrict__ hidden,  // [64][1024] f32
    const float* __restrict__ bias,    // [2][3072] f32
    const float* __restrict__ kern,    // [256][3072] f32 (input kernel)
    const __bf16* __restrict__ Rt,     // [3072][1024] bf16
    char* __restrict__ rot,            // NSLOT * SLOT_B bytes
    float* __restrict__ out)           // [64][512][1024] f32 (+ state tail)
{
    extern __shared__ char lds_raw[];
    float*  pacc  = (float*)lds_raw;
    __bf16* hpack = (__bf16*)(lds_raw + PACC_BYTES); // [16][16]

    const int tid  = threadIdx.x;
    const int lane = tid & 63;
    const int wv   = tid >> 6;        // 0..3
    const int rc   = lane & 15;
    const int kg   = lane >> 4;
    const int bid  = blockIdx.x;
    const int c    = bid & 63;
    const int rt   = bid >> 6;
    const int u    = (c << 4) + rc;
    const int row0 = rt << 4;

    if (wv == 0) __builtin_amdgcn_s_setprio(1);

    const int gu0 = u;
    const int gu1 = U_DIM + u;
    const int gu2 = 2 * U_DIM + u;
    const int xk0 = wv << 6;          // X k-slice base

    // ---- hoist ALL B-fragments into registers (once) ----
    bf16x8 whz[8], whr[8], whh[8];    // H-weights: contiguous 16B from Rt
#pragma unroll
    for (int ki = 0; ki < 8; ++ki) {
        const int col = (wv << 8) + (ki << 5) + (kg << 3);
        whz[ki] = *(const bf16x8*)(Rt + (size_t)gu0 * U_DIM + col);
        whr[ki] = *(const bf16x8*)(Rt + (size_t)gu1 * U_DIM + col);
        whh[ki] = *(const bf16x8*)(Rt + (size_t)gu2 * U_DIM + col);
    }
    bf16x8 wxz[2], wxr[2], wxh[2];    // X-weights: scattered one-time f32
#pragma unroll
    for (int fx = 0; fx < 2; ++fx) {
#pragma unroll
        for (int e = 0; e < 8; ++e) {
            const int k = xk0 + fx * 32 + (kg << 3) + e;
            wxz[fx][e] = (__bf16)kern[(size_t)k * G3 + gu0];
            wxr[fx][e] = (__bf16)kern[(size_t)k * G3 + gu1];
            wxh[fx][e] = (__bf16)kern[(size_t)k * G3 + gu2];
        }
    }

    // ---- per-thread invariants ----
    float hprev[4];
#pragma unroll
    for (int j = 0; j < 4; ++j)
        hprev[j] = hidden[(size_t)(row0 + (kg << 2) + j) * U_DIM + u];

    const float bz_ = bias[u]             + bias[G3 + u];
    const float br_ = bias[U_DIM + u]     + bias[G3 + U_DIM + u];
    const float bhx = bias[2 * U_DIM + u];
    const float bhr = bias[G3 + 2 * U_DIM + u];

    const float* xbase = x + (size_t)(row0 + rc) * (T_STEPS * F_DIM)
                           + xk0 + (kg << 3);

    const int grp_b = rt * GRP_B;
    const int lan_b = (wv << 13) + ((kg >> 1) << 9) + (rc << 5) + ((kg & 1) << 4);
    const int my_b  = grp_b + c * TILE_B + (lane << 3);

    int slot_r = 0, slot_w = 1, slot_p = 3;
    const u32x2 sentv = { SENT, SENT };

    for (int t = 0; t < T_STEPS; ++t) {
        f32x4 accZ  = {0.f, 0.f, 0.f, 0.f};
        f32x4 accR  = {0.f, 0.f, 0.f, 0.f};
        f32x4 accHX = {0.f, 0.f, 0.f, 0.f};
        f32x4 accHR = {0.f, 0.f, 0.f, 0.f};
        const int p = t & 1;

        // ---- spec-issue my 8 h(t-1) fragment loads (slot t%5) ----
        const char* hb = rot + slot_r * SLOT_B + grp_b + lan_b;
        bf16x8 hfrag[8];
#define HL(ki, m, lit)                                                         \
        asm volatile("global_load_dwordx4 %0, %1, off offset:" lit " sc0 sc1"  \
                     : "=v"(hfrag[ki]) : "v"(hb + (m) * 4096) : "memory");
#define HLOADS()                                                               \
        HL(0,0,"0") HL(1,0,"1024") HL(2,0,"2048") HL(3,0,"3072")               \
        HL(4,1,"0") HL(5,1,"1024") HL(6,1,"2048") HL(7,1,"3072")
        HLOADS()

        // ---- X phase: my 64-k slice, B-frags from registers ----
        const float* ap = xbase + t * F_DIM;
#pragma unroll
        for (int fx = 0; fx < 2; ++fx) {
            const float4 a0 = *(const float4*)(ap + fx * 32);
            const float4 a1 = *(const float4*)(ap + fx * 32 + 4);
            bf16x8 af;
            af[0] = (__bf16)a0.x; af[1] = (__bf16)a0.y;
            af[2] = (__bf16)a0.z; af[3] = (__bf16)a0.w;
            af[4] = (__bf16)a1.x; af[5] = (__bf16)a1.y;
            af[6] = (__bf16)a1.z; af[7] = (__bf16)a1.w;
            accZ  = __builtin_amdgcn_mfma_f32_16x16x32_bf16(af, wxz[fx], accZ,  0, 0, 0);
            accR  = __builtin_amdgcn_mfma_f32_16x16x32_bf16(af, wxr[fx], accR,  0, 0, 0);
            accHX = __builtin_amdgcn_mfma_f32_16x16x32_bf16(af, wxh[fx], accHX, 0, 0, 0);
        }

        // ---- wave0: store out[t-1] (fills remaining RTT) ----
        if (wv == 0 && t > 0) {
#pragma unroll
            for (int j = 0; j < 4; ++j) {
                const int row = row0 + (kg << 2) + j;
                out[((size_t)row * T_STEPS + (t - 1)) * U_DIM + u] = hprev[j];
            }
        }

        // ---- sentinel poll: my 8 fragments must be real data ----
        for (;;) {
            asm volatile("s_waitcnt vmcnt(0)" ::: "memory");
            __builtin_amdgcn_sched_barrier(0);
            int ok = 1;
#pragma unroll
            for (int ki = 0; ki < 8; ++ki) {
                const u32x4 w = __builtin_bit_cast(u32x4, hfrag[ki]);
                ok &= (w[0] != SENT) & (w[2] != SENT);
            }
            if (__all(ok)) break;
            HLOADS()
        }
#undef HLOADS
#undef HL

        // ---- H phase: 24 pure-register MFMAs ----
#pragma unroll
        for (int ki = 0; ki < 8; ++ki) {
            const bf16x8 af = hfrag[ki];
            accZ  = __builtin_amdgcn_mfma_f32_16x16x32_bf16(af, whz[ki], accZ,  0, 0, 0);
            accR  = __builtin_amdgcn_mfma_f32_16x16x32_bf16(af, whr[ki], accR,  0, 0, 0);
            accHR = __builtin_amdgcn_mfma_f32_16x16x32_bf16(af, whh[ki], accHR, 0, 0, 0);
        }

        // ---- waves 1-3: dump partials (parity-buffered) ----
        if (wv != 0) {
            const int w1 = wv - 1;
            *(f32x4*)&pacc[(((p * 12) + 0 * 3 + w1) * 64 + lane) * 4] = accZ;
            *(f32x4*)&pacc[(((p * 12) + 1 * 3 + w1) * 64 + lane) * 4] = accR;
            *(f32x4*)&pacc[(((p * 12) + 2 * 3 + w1) * 64 + lane) * 4] = accHX;
            *(f32x4*)&pacc[(((p * 12) + 3 * 3 + w1) * 64 + lane) * 4] = accHR;
        }
        __syncthreads();

        // ---- wave 0: reduce, gates, publish (single 8B store), poison ----
        if (wv == 0) {
#pragma unroll
            for (int w1 = 0; w1 < 3; ++w1) {
                accZ  += *(const f32x4*)&pacc[(((p * 12) + 0 * 3 + w1) * 64 + lane) * 4];
                accR  += *(const f32x4*)&pacc[(((p * 12) + 1 * 3 + w1) * 64 + lane) * 4];
                accHX += *(const f32x4*)&pacc[(((p * 12) + 2 * 3 + w1) * 64 + lane) * 4];
                accHR += *(const f32x4*)&pacc[(((p * 12) + 3 * 3 + w1) * 64 + lane) * 4];
            }
#pragma unroll
            for (int j = 0; j < 4; ++j) {
                const float z  = sigmoidf_(accZ[j] + bz_);
                const float r  = sigmoidf_(accR[j] + br_);
                const float hh = tanhf_(accHX[j] + bhx + r * (accHR[j] + bhr));
                hprev[j] = z * hprev[j] + (1.f - z) * hh;
            }
#pragma unroll
            for (int j = 0; j < 4; ++j)
                hpack[(((kg << 2) + j) << 4) + rc] = (__bf16)hprev[j];
            const u32x2 hv = *(const u32x2*)(hpack + ((lane >> 2) << 4) + ((lane & 3) << 2));
            asm volatile("global_store_dwordx2 %0, %1, off sc0 sc1"
                         :: "v"(rot + slot_w * SLOT_B + my_b), "v"(hv) : "memory");
            asm volatile("global_store_dwordx2 %0, %1, off sc0 sc1"
                         :: "v"(rot + slot_p * SLOT_B + my_b), "v"(sentv) : "memory");
        }

        if (++slot_r == NSLOT) slot_r = 0;
        if (++slot_w == NSLOT) slot_w = 0;
        if (++slot_p == NSLOT) slot_p = 0;
    }

    // ---- final: out[T-1] + state tail (wave 0) ----
    if (wv == 0) {
#pragma unroll
        for (int j = 0; j < 4; ++j) {
            const int row = row0 + (kg << 2) + j;
            out[((size_t)row * T_STEPS + (T_STEPS - 1)) * U_DIM + u] = hprev[j];
            out[(size_t)B_ROWS * T_STEPS * U_DIM + (size_t)row * U_DIM + u] = hprev[j];
        }
    }
}

extern "C" void kernel_launch(void* const* d_in, const int* in_sizes, int n_in,
                              void* d_out, int out_size, void* d_ws, size_t ws_size,
                              hipStream_t stream)
{
    const float* x      = (const float*)d_in[0];  // [64,512,256]
    const float* hidden = (const float*)d_in[1];  // [64,1024]
    const float* kernel = (const float*)d_in[2];  // [256,3072]
    const float* rker   = (const float*)d_in[3];  // [1024,3072]
    const float* bias   = (const float*)d_in[4];  // [2,3072]
    float* out = (float*)d_out;

    const size_t rt_el = (size_t)G3 * U_DIM;
    __bf16* Rt = (__bf16*)d_ws;                   // 6.29 MB
    char* rot  = (char*)(Rt + rt_el);             // 640 KB (5 slots)

    hipLaunchKernelGGL(transpose_cvt_kernel, dim3(G3 / 32, U_DIM / 32), dim3(256),
                       0, stream, rker, Rt, U_DIM);
    hipLaunchKernelGGL(init_kernel, dim3(256), dim3(256), 0, stream, hidden, rot);

    void* kx = (void*)&x;  void* kh = (void*)&hidden; void* kb = (void*)&bias;
    void* kk = (void*)&kernel; void* kR = (void*)&Rt;
    void* kr = (void*)&rot; void* ko = (void*)&out;
    void* args[7] = { kx, kh, kb, kk, kR, kr, ko };

    auto kfn = gru_persistent;
    (void)hipFuncSetAttribute((const void*)kfn,
                              hipFuncAttributeMaxDynamicSharedMemorySize, LDS_BYTES);
    hipError_t ce = hipLaunchCooperativeKernel(kfn, dim3(256), dim3(256), args,
                                               LDS_BYTES, stream);
    if (ce != hipSuccess) {
        // Fallback: plain launch. 1 block/CU on 256 CUs -> all blocks
        // co-resident; the spin protocol remains deadlock-free.
        hipLaunchKernelGGL(gru_persistent, dim3(256), dim3(256), LDS_BYTES, stream,
                           x, hidden, bias, kernel, Rt, rot, out);
    }
}